// Round 3
// baseline (531.486 us; speedup 1.0000x reference)
//
#include <hip/hip_runtime.h>

// Nearest-voxel gather: out[i] = f[clip((x[i]+1)/h,0,255) per axis], h=2/255.
// N = 2^24 points, f = 256^3 float32 (67 MB; > 32MB aggregate L2, < 256MB L3).
// R2 measured: FETCH 636MB (= 201MB x-stream + ~440MB random 64B line fills,
// matches Poisson-reuse model), 3.57 TB/s combined, VALUBusy 10.7%.
// R3 experiment: MLP 4 -> 16 gathers/thread to test latency-bound vs
// fabric/transaction-bound.

typedef float f32x4 __attribute__((ext_vector_type(4)));

__device__ __forceinline__ int vox_idx(float v) {
    // Bit-match reference: f32 IEEE divide by h (no fast-math reciprocal).
    const float h = 2.0f / 255.0f;
    float p = (v + 1.0f) / h;
    p = fminf(fmaxf(p, 0.0f), 255.0f);
    return (int)p;  // p >= 0, truncation == astype(int32)
}

__global__ __launch_bounds__(256) void voxel_gather_kernel(
    const float* __restrict__ x, const float* __restrict__ f,
    float* __restrict__ out, int n16)
{
    int t = blockIdx.x * blockDim.x + threadIdx.x;
    if (t >= n16) return;

    // 16 points per thread: 48 contiguous floats = 12 x 16B loads.
    const f32x4* x4 = (const f32x4*)x;
    f32x4 xv[12];
#pragma unroll
    for (int j = 0; j < 12; ++j)
        xv[j] = __builtin_nontemporal_load(&x4[12 * t + j]);

    // Flat coordinate view (SROA keeps this in registers: all indices constant
    // after full unroll).
    const float* c = (const float*)xv;
    int idx[16];
#pragma unroll
    for (int k = 0; k < 16; ++k)
        idx[k] = (vox_idx(c[3 * k + 0]) << 16) |
                 (vox_idx(c[3 * k + 1]) << 8) |
                  vox_idx(c[3 * k + 2]);

    // 16 independent gathers in flight before any use.
    f32x4 o[4];
    float* ov = (float*)o;
#pragma unroll
    for (int k = 0; k < 16; ++k)
        ov[k] = f[idx[k]];

#pragma unroll
    for (int j = 0; j < 4; ++j)
        __builtin_nontemporal_store(o[j], &((f32x4*)out)[4 * t + j]);
}

extern "C" void kernel_launch(void* const* d_in, const int* in_sizes, int n_in,
                              void* d_out, int out_size, void* d_ws, size_t ws_size,
                              hipStream_t stream) {
    const float* x = (const float*)d_in[0];  // (N, 3) float32
    const float* f = (const float*)d_in[1];  // (256,256,256) float32
    float* out = (float*)d_out;              // (N,) float32

    int n = in_sizes[0] / 3;                 // 16777216 points
    int n16 = n / 16;                        // 16 points per thread
    dim3 block(256);
    dim3 grid((n16 + block.x - 1) / block.x);
    voxel_gather_kernel<<<grid, block, 0, stream>>>(x, f, out, n16);
}

// Round 4
// 429.778 us; speedup vs baseline: 1.2367x; 1.2367x over previous
//
#include <hip/hip_runtime.h>

// Nearest-voxel gather: out[i] = f[clip((x[i]+1)/h,0,255) per axis], h=2/255.
// N = 2^24 points, f = 256^3 float32 (67 MB; > 32MB aggregate L2, < 256MB L3).
//
// R2 (4 pts/thread, 48B-lane-stride loads): 197us, FETCH 636MB, WRITE 65MB.
// R3 (16 pts/thread, 192B-lane-stride): 287us REGRESSION — WRITE 164MB (partial
//   -line nontemporal stores), FETCH 751MB (per-instr footprint 12KB broke
//   line reuse). Lesson: per-instruction lane coalescing dominates.
// R4: LDS-staged x (perfectly coalesced 16B/lane streams), stride-256 point
//   assignment (coalesced 4B/lane stores, conflict-free LDS reads), 8
//   independent gathers/thread for MLP.

typedef float f32x4 __attribute__((ext_vector_type(4)));

__device__ __forceinline__ int vox_idx(float v) {
    // Bit-match reference: f32 IEEE divide by h (no fast-math reciprocal).
    const float h = 2.0f / 255.0f;
    float p = (v + 1.0f) / h;
    p = fminf(fmaxf(p, 0.0f), 255.0f);
    return (int)p;  // p >= 0, truncation == astype(int32)
}

#define P 8                               // points per thread
#define BLK 256
#define PTS_PER_BLK (P * BLK)             // 2048 points
#define F4_PER_BLK (PTS_PER_BLK * 3 / 4)  // 1536 float4 = 24 KB

__global__ __launch_bounds__(256) void voxel_gather_kernel(
    const float* __restrict__ x, const float* __restrict__ f,
    float* __restrict__ out)
{
    __shared__ float lds[PTS_PER_BLK * 3];  // 24 KB -> 6 blocks/CU

    const int tid = threadIdx.x;
    const long long blk = blockIdx.x;

    // Phase 1: coalesced stream global -> LDS. Lane-contiguous float4:
    // 64 lanes x 16 B = 1 KB contiguous per instruction.
    const f32x4* x4 = (const f32x4*)x + blk * F4_PER_BLK;
#pragma unroll
    for (int j = 0; j < 6; ++j) {
        f32x4 v = __builtin_nontemporal_load(&x4[tid + BLK * j]);
        ((f32x4*)lds)[tid + BLK * j] = v;
    }
    __syncthreads();

    // Phase 2: thread handles points tid, tid+256, ... -> LDS reads are
    // lane-stride-3 floats (coprime-ish with 32 banks, <=2-way, free).
    int idx[P];
#pragma unroll
    for (int j = 0; j < P; ++j) {
        int p = tid + BLK * j;
        float cx = lds[3 * p + 0];
        float cy = lds[3 * p + 1];
        float cz = lds[3 * p + 2];
        idx[j] = (vox_idx(cx) << 16) | (vox_idx(cy) << 8) | vox_idx(cz);
    }

    // 8 independent cached gathers in flight (f stays L2/L3-resident).
    float r[P];
#pragma unroll
    for (int j = 0; j < P; ++j) r[j] = f[idx[j]];

    // Coalesced full-line stores: 64 lanes x 4 B contiguous per instruction.
    float* ob = out + blk * PTS_PER_BLK;
#pragma unroll
    for (int j = 0; j < P; ++j)
        __builtin_nontemporal_store(r[j], &ob[tid + BLK * j]);
}

extern "C" void kernel_launch(void* const* d_in, const int* in_sizes, int n_in,
                              void* d_out, int out_size, void* d_ws, size_t ws_size,
                              hipStream_t stream) {
    const float* x = (const float*)d_in[0];  // (N, 3) float32
    const float* f = (const float*)d_in[1];  // (256,256,256) float32
    float* out = (float*)d_out;              // (N,) float32

    int n = in_sizes[0] / 3;                 // 16777216 points
    int nblk = n / PTS_PER_BLK;              // 8192 blocks, no tail (n = 2^24)
    voxel_gather_kernel<<<dim3(nblk), dim3(BLK), 0, stream>>>(x, f, out);
}